// Round 19
// baseline (75.813 us; speedup 1.0000x reference)
//
#include <hip/hip_runtime.h>
#include <math.h>

#define BB 16
#define NN 4096
#define DD 128
#define KK 1024
#define NPTS (BB*NN)

typedef _Float16 half8 __attribute__((ext_vector_type(8)));
typedef float f32x4 __attribute__((ext_vector_type(4)));

static __device__ __forceinline__ uint pack2(float a, float b) {
    _Float16 ha = (_Float16)a, hb = (_Float16)b;
    unsigned short ua = __builtin_bit_cast(unsigned short, ha);
    unsigned short ub = __builtin_bit_cast(unsigned short, hb);
    return (uint)ua | ((uint)ub << 16);
}

typedef __attribute__((address_space(1))) const void as1_void;
typedef __attribute__((address_space(3))) void as3_void;
static __device__ __forceinline__ void gld16(const void* g, void* l) {
    // async global->LDS, 16B/lane; LDS dest = uniform base + lane*16 (HW rule)
    __builtin_amdgcn_global_load_lds((as1_void*)g, (as3_void*)l, 16, 0, 0);
}

#define VMWAIT4 asm volatile("s_waitcnt vmcnt(4)" ::: "memory")
#define VMWAIT2 asm volatile("s_waitcnt vmcnt(2)" ::: "memory")
#define VMWAIT0 asm volatile("s_waitcnt vmcnt(0)" ::: "memory")
#define LGKM0   asm volatile("s_waitcnt lgkmcnt(0)" ::: "memory")
#define RBARRIER do { __builtin_amdgcn_s_barrier(); asm volatile("" ::: "memory"); } while (0)
#define SCHEDB  __builtin_amdgcn_sched_barrier(0)

// ---------------- kernel 0 (fused): centroid fragments + squared norms ----------------
// Blocks [0,64): pre-permute centroids into 16x16x32 B-fragment order
//   fragment (nt, c, lane) = cent row (nt*16 + (lane&15)), d in [c*32+(lane>>4)*8, +8),
//   split fp16 hi + (lo*1024), packed uint4 (HW-verified layout, R12-R17 pass).
// Blocks [64,320): cn[row] = ||c_row||^2 in double (wave per row).
__global__ void prep_kernel(const float* __restrict__ cent,
                            uint4* __restrict__ cfh, uint4* __restrict__ cfl,
                            float* __restrict__ cnorm) {
    if (blockIdx.x < 64) {
        const int gid = blockIdx.x * 256 + threadIdx.x;   // [0, 64*4*64) = 16384
        const int nt = gid >> 8;
        const int c = (gid >> 6) & 3;
        const int lane = gid & 63;
        const int row = nt * 16 + (lane & 15);
        const int d0 = c * 32 + (lane >> 4) * 8;
        const float* src = cent + (size_t)row * DD + d0;
        float v[8];
#pragma unroll
        for (int i = 0; i < 8; ++i) v[i] = src[i];
        float lo[8];
#pragma unroll
        for (int i = 0; i < 8; ++i) {
            _Float16 h = (_Float16)v[i];
            lo[i] = (v[i] - (float)h) * 1024.f;
        }
        uint4 h4, l4;
        h4.x = pack2(v[0], v[1]); h4.y = pack2(v[2], v[3]);
        h4.z = pack2(v[4], v[5]); h4.w = pack2(v[6], v[7]);
        l4.x = pack2(lo[0], lo[1]); l4.y = pack2(lo[2], lo[3]);
        l4.z = pack2(lo[4], lo[5]); l4.w = pack2(lo[6], lo[7]);
        cfh[gid] = h4;
        cfl[gid] = l4;
    } else {
        const int w = threadIdx.x >> 6, lane = threadIdx.x & 63;
        const int row = (blockIdx.x - 64) * 4 + w;
        float2 v = ((const float2*)(cent + (size_t)row * DD))[lane];
        double s = (double)v.x * v.x + (double)v.y * v.y;
#pragma unroll
        for (int m = 1; m < 64; m <<= 1) s += __shfl_xor(s, m);
        if (lane == 0) cnorm[row] = (float)s;
    }
}

// ---------------- kernel 1: nearest-centroid, cross-phase B-register double buffer ----------------
// 1024 blocks x 4 waves (full K); wave w owns points [block*64 + w*16, +16).
// 64 phases, 4-slot ring (stage s -> slot s&3), LDS 36.9KB -> 4 blocks/CU,
// VGPR target ~125 <= 128 -> 4 waves/SIMD.
// Phase p: MFMA on CUR regs (stage p, read LAST phase -> no lgkm dependency);
//   pre-read stage p+1 -> NXT regs; issue stage p+4 (slot p&3: readers passed
//   the p-1 barrier); SCHEDB pins reads+issue above the MFMAs;
//   end: LGKM0 (pre-read had a full MFMA block of cover); vmcnt(4); barrier.
// Ledger: end of phase p -> outstanding {p+3,p+4} -> landed <= p+2 -> phase
// p+1's pre-read of stage p+2 safe (one stage of margin). Tail 4->2->0->lgkm.
__launch_bounds__(256, 4)
__global__ void assign_mfma13(const float* __restrict__ x,
                              const uint4* __restrict__ cfh, const uint4* __restrict__ cfl,
                              const float* __restrict__ cn,
                              float* __restrict__ min_d, int* __restrict__ nearest) {
    __shared__ uint4 ring[4][8][64];   // [slot][frag-row: 0-3 hi(c), 4-7 lo(c)][lane]
    __shared__ float cnS[KK];

    const int tid = threadIdx.x;
    const int lane = tid & 63;
    const int w = tid >> 6;
    const int l15 = lane & 15;
    const int lg = lane >> 4;          // k-group 0..3
    const int p0 = blockIdx.x * 64 + w * 16;

#define STAGE_ISSUE(S)                                                              \
    { const int s_ = (S); const int sl_ = s_ & 3;                                   \
      gld16(cfh + ((size_t)s_ * 4 + w) * 64 + lane, &ring[sl_][w][0]);              \
      gld16(cfl + ((size_t)s_ * 4 + w) * 64 + lane, &ring[sl_][w + 4][0]); }

    // prologue: issue stages 0..3 (they fly under the cn/x loads)
#pragma unroll
    for (int s = 0; s < 4; ++s) STAGE_ISSUE(s)

    // cn -> LDS (consumed in epilogues; keeps the loop free of global loads)
    ((float4*)cnS)[tid] = ((const float4*)cn)[tid];

    // A fragments: lane covers row l15, k = c*32 + lg*8 + i (same split as R3-R17)
    half8 ahi[4], alo[4];
    float xs = 0.f;
    const float4* xrow = (const float4*)(x + (size_t)(p0 + l15) * DD);
#pragma unroll
    for (int c = 0; c < 4; ++c) {
        float4 v0 = xrow[c * 8 + lg * 2];
        float4 v1 = xrow[c * 8 + lg * 2 + 1];
        float vv[8] = {v0.x, v0.y, v0.z, v0.w, v1.x, v1.y, v1.z, v1.w};
#pragma unroll
        for (int i = 0; i < 8; ++i) {
            _Float16 h = (_Float16)vv[i];
            ahi[c][i] = h;
            alo[c][i] = (_Float16)((vv[i] - (float)h) * 1024.f);
            xs = fmaf(vv[i], vv[i], xs);
        }
    }
    // lanes {l15, l15+16, l15+32, l15+48} hold disjoint k-quarters of row l15
    xs += __shfl_xor(xs, 16);
    xs += __shfl_xor(xs, 32);          // every lane: ||x_{l15}||^2

    float best[4];
    int bk[4];
#pragma unroll
    for (int r = 0; r < 4; ++r) { best[r] = INFINITY; bk[r] = 0; }

    VMWAIT0;    // stages 0..3 + x + cn loads all landed (prologue-only full drain)
    LGKM0;      // own cnS ds_write done
    RBARRIER;   // all waves: stages 0..3 + cnS visible
    SCHEDB;

    // pre-read stage 0 -> rA (CUR for phase 0). NOTE: names avoid the BB macro.
    uint4 rA[8], rB[8];
#pragma unroll
    for (int j = 0; j < 8; ++j) rA[j] = ring[0][j][lane];
    LGKM0;
    SCHEDB;

#define DO_PHASE(NT, CURB, NXTB, DOREAD, DOSTG, WAITSEQ)                            \
    {                                                                               \
        if (DOREAD) {                                                               \
            const int rs_ = ((NT) + 1) & 3;                                         \
            _Pragma("unroll")                                                       \
            for (int j = 0; j < 8; ++j) NXTB[j] = ring[rs_][j][lane];               \
        }                                                                           \
        if (DOSTG) STAGE_ISSUE((NT) + 4)                                            \
        SCHEDB;   /* reads+issue pinned above; MFMAs below run on CUR regs */       \
        f32x4 hh, cr;                                                               \
        _Pragma("unroll")                                                           \
        for (int i = 0; i < 4; ++i) { hh[i] = 0.f; cr[i] = 0.f; }                   \
        __builtin_amdgcn_s_setprio(1);                                              \
        hh = __builtin_amdgcn_mfma_f32_16x16x32_f16(ahi[0], __builtin_bit_cast(half8, CURB[0]), hh, 0, 0, 0); \
        cr = __builtin_amdgcn_mfma_f32_16x16x32_f16(alo[0], __builtin_bit_cast(half8, CURB[0]), cr, 0, 0, 0); \
        hh = __builtin_amdgcn_mfma_f32_16x16x32_f16(ahi[1], __builtin_bit_cast(half8, CURB[1]), hh, 0, 0, 0); \
        cr = __builtin_amdgcn_mfma_f32_16x16x32_f16(alo[1], __builtin_bit_cast(half8, CURB[1]), cr, 0, 0, 0); \
        hh = __builtin_amdgcn_mfma_f32_16x16x32_f16(ahi[2], __builtin_bit_cast(half8, CURB[2]), hh, 0, 0, 0); \
        cr = __builtin_amdgcn_mfma_f32_16x16x32_f16(alo[2], __builtin_bit_cast(half8, CURB[2]), cr, 0, 0, 0); \
        hh = __builtin_amdgcn_mfma_f32_16x16x32_f16(ahi[3], __builtin_bit_cast(half8, CURB[3]), hh, 0, 0, 0); \
        cr = __builtin_amdgcn_mfma_f32_16x16x32_f16(alo[3], __builtin_bit_cast(half8, CURB[3]), cr, 0, 0, 0); \
        cr = __builtin_amdgcn_mfma_f32_16x16x32_f16(ahi[0], __builtin_bit_cast(half8, CURB[4]), cr, 0, 0, 0); \
        cr = __builtin_amdgcn_mfma_f32_16x16x32_f16(ahi[1], __builtin_bit_cast(half8, CURB[5]), cr, 0, 0, 0); \
        cr = __builtin_amdgcn_mfma_f32_16x16x32_f16(ahi[2], __builtin_bit_cast(half8, CURB[6]), cr, 0, 0, 0); \
        cr = __builtin_amdgcn_mfma_f32_16x16x32_f16(ahi[3], __builtin_bit_cast(half8, CURB[7]), cr, 0, 0, 0); \
        __builtin_amdgcn_s_setprio(0);                                              \
        {   const float cnv_ = cnS[(NT) * 16 + l15];                                \
            const int kcur_ = (NT) * 16 + l15;                                      \
            _Pragma("unroll")                                                       \
            for (int r = 0; r < 4; ++r) {                                           \
                float v_ = cnv_ - 2.f * hh[r] - 0.001953125f * cr[r];               \
                if (v_ < best[r]) { best[r] = v_; bk[r] = kcur_; }                  \
            }                                                                       \
        }                                                                           \
        WAITSEQ;                                                                    \
    }

#define W4B do { LGKM0; VMWAIT4; RBARRIER; SCHEDB; } while (0)
#define W2B do { LGKM0; VMWAIT2; RBARRIER; SCHEDB; } while (0)
#define W0B do { LGKM0; VMWAIT0; RBARRIER; SCHEDB; } while (0)
#define WLG do { LGKM0; SCHEDB; } while (0)
#define WN  do { } while (0)

    // phases 0..59 (x2 unroll, ping-pong rA/rB); phase p issues stage p+4
#pragma unroll 1
    for (int t = 0; t < 60; t += 2) {
        DO_PHASE(t,     rA, rB, 1, 1, W4B)   // pre-read stage t+1
        DO_PHASE(t + 1, rB, rA, 1, 1, W4B)   // pre-read stage t+2
    }
    // tail: stages 60..63 already staged; drain 4 -> 2 -> 0
    DO_PHASE(60, rA, rB, 1, 0, W2B)   // pre-read 61 (landed <= 61 by end of 59)
    DO_PHASE(61, rB, rA, 1, 0, W0B)   // pre-read 62 (landed <= 62 by end of 60)
    DO_PHASE(62, rA, rB, 1, 0, WLG)   // pre-read 63 (all landed); no more writes -> no barrier
    DO_PHASE(63, rB, rA, 0, 0, WN)    // last tile
#undef DO_PHASE
#undef STAGE_ISSUE
#undef W4B
#undef W2B
#undef W0B
#undef WLG
#undef WN

    // argmin across the 16 centroid-columns within each 16-lane group
    // (masks < 16 keep lg fixed); numpy tie-break: smaller k
#pragma unroll
    for (int r = 0; r < 4; ++r) {
        float bv = best[r]; int bi = bk[r];
#pragma unroll
        for (int m = 1; m < 16; m <<= 1) {
            float ov = __shfl_xor(bv, m);
            int oi = __shfl_xor(bi, m);
            if (ov < bv || (ov == bv && oi < bi)) { bv = ov; bi = oi; }
        }
        best[r] = bv; bk[r] = bi;
    }

    // D layout (m89-verified): col = lane&15, row = (lane>>4)*4 + r
    float xnv[4];
#pragma unroll
    for (int r = 0; r < 4; ++r)
        xnv[r] = __shfl(xs, lg * 4 + r);   // xs of point (lg*4+r) lives in lane (lg*4+r)

    if (l15 == 0) {
#pragma unroll
        for (int r = 0; r < 4; ++r) {
            int m = lg * 4 + r;
            float sq = xnv[r] + best[r];
            min_d[p0 + m] = sqrtf(fmaxf(sq, 0.f));
            nearest[p0 + m] = bk[r];
        }
    }
}

// ---------------- kernel 2: per-batch stats + histogram + normalize (1024 threads) ----------------
__global__ void finalize_kernel(const float* __restrict__ min_d, const int* __restrict__ nearest,
                                const float* __restrict__ weights, float* __restrict__ out) {
    __shared__ float red[1024];
    __shared__ int hist[KK];
    __shared__ float bc[2];  // mean, thr
    const int b = blockIdx.x;
    const int tid = threadIdx.x;
    const float* md = min_d + (size_t)b * NN;
    const int* nr = nearest + (size_t)b * NN;

    // pass A: mean (two-pass std to match numpy numerics)
    float s = 0.f;
#pragma unroll
    for (int j = 0; j < NN / 1024; ++j) s += md[tid + 1024 * j];
    red[tid] = s;
    __syncthreads();
    for (int off = 512; off > 0; off >>= 1) {
        if (tid < off) red[tid] += red[tid + off];
        __syncthreads();
    }
    if (tid == 0) bc[0] = red[0] / (float)NN;
    __syncthreads();
    const float mean = bc[0];

    // pass B: sum of squared deviations -> thr = mean + std(ddof=1)
    float ss = 0.f;
#pragma unroll
    for (int j = 0; j < NN / 1024; ++j) {
        float v = md[tid + 1024 * j] - mean;
        ss += v * v;
    }
    red[tid] = ss;
    __syncthreads();
    for (int off = 512; off > 0; off >>= 1) {
        if (tid < off) red[tid] += red[tid + off];
        __syncthreads();
    }
    if (tid == 0) bc[1] = mean + sqrtf(red[0] / (float)(NN - 1));

    // histogram of masked assignments
    hist[tid] = 0;
    __syncthreads();
    const float thr = bc[1];
#pragma unroll
    for (int j = 0; j < NN / 1024; ++j) {
        int i = tid + 1024 * j;
        if (md[i] < thr) atomicAdd(&hist[nr[i]], 1);
    }
    __syncthreads();

    // asmk = counts*weights; L2-normalize the row (one k per thread)
    const float a = (float)hist[tid] * weights[tid];
    red[tid] = a * a;
    __syncthreads();
    for (int off = 512; off > 0; off >>= 1) {
        if (tid < off) red[tid] += red[tid + off];
        __syncthreads();
    }
    const float norm = sqrtf(red[0]);
    const float scale = 1.f / fmaxf(norm, 1e-12f);
    out[(size_t)b * KK + tid] = a * scale;
}

extern "C" void kernel_launch(void* const* d_in, const int* in_sizes, int n_in,
                              void* d_out, int out_size, void* d_ws, size_t ws_size,
                              hipStream_t stream) {
    const float* x = (const float*)d_in[0];
    const float* cent = (const float*)d_in[1];
    const float* weights = (const float*)d_in[2];
    float* out = (float*)d_out;

    char* ws = (char*)d_ws;
    float* min_d   = (float*)(ws + 0);
    int*   nearest = (int*)  (ws + 262144);
    float* cn      = (float*)(ws + 524288);
    uint4* cfh     = (uint4*)(ws + 528384);
    uint4* cfl     = (uint4*)(ws + 790528);

    prep_kernel<<<320, 256, 0, stream>>>(cent, cfh, cfl, cn);
    assign_mfma13<<<NPTS / 64, 256, 0, stream>>>(x, cfh, cfl, cn, min_d, nearest);
    finalize_kernel<<<BB, 1024, 0, stream>>>(min_d, nearest, weights, out);
}

// Round 22
// 72.497 us; speedup vs baseline: 1.0457x; 1.0457x over previous
//
#include <hip/hip_runtime.h>
#include <math.h>

#define BB 16
#define NN 4096
#define DD 128
#define KK 1024
#define NPTS (BB*NN)

typedef _Float16 half8 __attribute__((ext_vector_type(8)));
typedef float f32x4 __attribute__((ext_vector_type(4)));

static __device__ __forceinline__ uint pack2(float a, float b) {
    _Float16 ha = (_Float16)a, hb = (_Float16)b;
    unsigned short ua = __builtin_bit_cast(unsigned short, ha);
    unsigned short ub = __builtin_bit_cast(unsigned short, hb);
    return (uint)ua | ((uint)ub << 16);
}

typedef __attribute__((address_space(1))) const void as1_void;
typedef __attribute__((address_space(3))) void as3_void;
static __device__ __forceinline__ void gld16(const void* g, void* l) {
    // async global->LDS, 16B/lane; LDS dest = uniform base + lane*16 (HW rule)
    __builtin_amdgcn_global_load_lds((as1_void*)g, (as3_void*)l, 16, 0, 0);
}

// counted waits + raw barrier (loads stay in flight ACROSS barriers — T3/T4)
#define VMWAIT4 asm volatile("s_waitcnt vmcnt(4)" ::: "memory")
#define VMWAIT2 asm volatile("s_waitcnt vmcnt(2)" ::: "memory")
#define VMWAIT0 asm volatile("s_waitcnt vmcnt(0)" ::: "memory")
#define LGKM0   asm volatile("s_waitcnt lgkmcnt(0)" ::: "memory")
#define RBARRIER do { __builtin_amdgcn_s_barrier(); asm volatile("" ::: "memory"); } while (0)
#define SCHEDB  __builtin_amdgcn_sched_barrier(0)

// ---------------- kernel 0 (fused): centroid fragments + squared norms ----------------
// Blocks [0,64): pre-permute centroids into 16x16x32 B-fragment order
//   fragment (nt, c, lane) = cent row (nt*16 + (lane&15)), d in [c*32+(lane>>4)*8, +8),
//   split fp16 hi + (lo*1024), packed uint4 (HW-verified layout, R12-R17 pass).
// Blocks [64,320): cn[row] = ||c_row||^2 in double (wave per row).
__global__ void prep_kernel(const float* __restrict__ cent,
                            uint4* __restrict__ cfh, uint4* __restrict__ cfl,
                            float* __restrict__ cnorm) {
    if (blockIdx.x < 64) {
        const int gid = blockIdx.x * 256 + threadIdx.x;   // [0, 64*4*64) = 16384
        const int nt = gid >> 8;
        const int c = (gid >> 6) & 3;
        const int lane = gid & 63;
        const int row = nt * 16 + (lane & 15);
        const int d0 = c * 32 + (lane >> 4) * 8;
        const float* src = cent + (size_t)row * DD + d0;
        float v[8];
#pragma unroll
        for (int i = 0; i < 8; ++i) v[i] = src[i];
        float lo[8];
#pragma unroll
        for (int i = 0; i < 8; ++i) {
            _Float16 h = (_Float16)v[i];
            lo[i] = (v[i] - (float)h) * 1024.f;
        }
        uint4 h4, l4;
        h4.x = pack2(v[0], v[1]); h4.y = pack2(v[2], v[3]);
        h4.z = pack2(v[4], v[5]); h4.w = pack2(v[6], v[7]);
        l4.x = pack2(lo[0], lo[1]); l4.y = pack2(lo[2], lo[3]);
        l4.z = pack2(lo[4], lo[5]); l4.w = pack2(lo[6], lo[7]);
        cfh[gid] = h4;
        cfl[gid] = l4;
    } else {
        const int w = threadIdx.x >> 6, lane = threadIdx.x & 63;
        const int row = (blockIdx.x - 64) * 4 + w;
        float2 v = ((const float2*)(cent + (size_t)row * DD))[lane];
        double s = (double)v.x * v.x + (double)v.y * v.y;
#pragma unroll
        for (int m = 1; m < 64; m <<= 1) s += __shfl_xor(s, m);
        if (lane == 0) cnorm[row] = (float)s;
    }
}

// ---------------- kernel 1: nearest-centroid, 16x16x32 MFMA, 4 waves/SIMD ----------------
// R12's proven structure: 1024 blocks x 4 waves; wave w owns points [block*64+w*16,+16).
// 64 phases, 8KB stage (16 cents), 4-slot ring, stage s -> slot s&3; phase t reads
// stage t, issues stage t+3, counted vmcnt(4)+raw barrier (tail 4->2->0).
// Merged cr chain (R13-validated order), zero4 C-in for chain heads, hi/lo split
// reads with b-register reuse. Best verified configuration (R14: 72.47us total).
__launch_bounds__(256, 4)
__global__ void assign_mfma10(const float* __restrict__ x,
                              const uint4* __restrict__ cfh, const uint4* __restrict__ cfl,
                              const float* __restrict__ cn,
                              float* __restrict__ min_d, int* __restrict__ nearest) {
    __shared__ uint4 ring[4][8][64];   // [slot][frag-row: 0-3 hi(c), 4-7 lo(c)][lane]
    __shared__ float cnS[KK];

    const int tid = threadIdx.x;
    const int lane = tid & 63;
    const int w = tid >> 6;
    const int l15 = lane & 15;
    const int lg = lane >> 4;          // k-group 0..3
    const int p0 = blockIdx.x * 64 + w * 16;

#define STAGE_ISSUE(S)                                                              \
    { const int s_ = (S); const int sl_ = s_ & 3;                                   \
      gld16(cfh + ((size_t)s_ * 4 + w) * 64 + lane, &ring[sl_][w][0]);              \
      gld16(cfl + ((size_t)s_ * 4 + w) * 64 + lane, &ring[sl_][w + 4][0]); }

    // prologue: issue stages 0..2 first (fly under the cn/x loads)
#pragma unroll
    for (int s = 0; s < 3; ++s) STAGE_ISSUE(s)

    // cn -> LDS (consumed in epilogues; keeps the loop free of global loads)
    ((float4*)cnS)[tid] = ((const float4*)cn)[tid];

    // A fragments: lane covers row l15, k = c*32 + lg*8 + i (same split as R3-R13)
    half8 ahi[4], alo[4];
    float xs = 0.f;
    const float4* xrow = (const float4*)(x + (size_t)(p0 + l15) * DD);
#pragma unroll
    for (int c = 0; c < 4; ++c) {
        float4 v0 = xrow[c * 8 + lg * 2];
        float4 v1 = xrow[c * 8 + lg * 2 + 1];
        float vv[8] = {v0.x, v0.y, v0.z, v0.w, v1.x, v1.y, v1.z, v1.w};
#pragma unroll
        for (int i = 0; i < 8; ++i) {
            _Float16 h = (_Float16)vv[i];
            ahi[c][i] = h;
            alo[c][i] = (_Float16)((vv[i] - (float)h) * 1024.f);
            xs = fmaf(vv[i], vv[i], xs);
        }
    }
    // lanes {l15, l15+16, l15+32, l15+48} hold disjoint k-quarters of row l15
    xs += __shfl_xor(xs, 16);
    xs += __shfl_xor(xs, 32);          // every lane: ||x_{l15}||^2

    float best[4];
    int bk[4];
#pragma unroll
    for (int r = 0; r < 4; ++r) { best[r] = INFINITY; bk[r] = 0; }

    f32x4 zero4;                       // persistent zero C-in for MFMA chain heads
#pragma unroll
    for (int i = 0; i < 4; ++i) zero4[i] = 0.f;

    VMWAIT4;    // x/cn consumption drained older gld16s; stage 0 landed
    LGKM0;      // own cnS ds_write done
    RBARRIER;   // all waves: stage 0 + cnS visible
    SCHEDB;

#define DO_PHASE(NT, SST, DOSTG, WAITSEQ)                                           \
    {                                                                               \
        const int sl_ = (NT) & 3;                                                   \
        /* chunk 1: hi fragments -> hh chain + alo*bh half of cr (R13 order) */     \
        uint4 b0 = ring[sl_][0][lane], b1 = ring[sl_][1][lane];                     \
        uint4 b2 = ring[sl_][2][lane], b3 = ring[sl_][3][lane];                     \
        if (DOSTG) STAGE_ISSUE(SST)                                                 \
        f32x4 hh, cr;                                                               \
        __builtin_amdgcn_s_setprio(1);                                              \
        hh = __builtin_amdgcn_mfma_f32_16x16x32_f16(ahi[0], __builtin_bit_cast(half8, b0), zero4, 0, 0, 0); \
        cr = __builtin_amdgcn_mfma_f32_16x16x32_f16(alo[0], __builtin_bit_cast(half8, b0), zero4, 0, 0, 0); \
        hh = __builtin_amdgcn_mfma_f32_16x16x32_f16(ahi[1], __builtin_bit_cast(half8, b1), hh, 0, 0, 0);    \
        cr = __builtin_amdgcn_mfma_f32_16x16x32_f16(alo[1], __builtin_bit_cast(half8, b1), cr, 0, 0, 0);    \
        hh = __builtin_amdgcn_mfma_f32_16x16x32_f16(ahi[2], __builtin_bit_cast(half8, b2), hh, 0, 0, 0);    \
        cr = __builtin_amdgcn_mfma_f32_16x16x32_f16(alo[2], __builtin_bit_cast(half8, b2), cr, 0, 0, 0);    \
        hh = __builtin_amdgcn_mfma_f32_16x16x32_f16(ahi[3], __builtin_bit_cast(half8, b3), hh, 0, 0, 0);    \
        cr = __builtin_amdgcn_mfma_f32_16x16x32_f16(alo[3], __builtin_bit_cast(half8, b3), cr, 0, 0, 0);    \
        __builtin_amdgcn_s_setprio(0);                                              \
        /* chunk 2: lo fragments (reuse b0..b3) -> ahi*bl half of cr */             \
        b0 = ring[sl_][4][lane]; b1 = ring[sl_][5][lane];                           \
        b2 = ring[sl_][6][lane]; b3 = ring[sl_][7][lane];                           \
        __builtin_amdgcn_s_setprio(1);                                              \
        cr = __builtin_amdgcn_mfma_f32_16x16x32_f16(ahi[0], __builtin_bit_cast(half8, b0), cr, 0, 0, 0);    \
        cr = __builtin_amdgcn_mfma_f32_16x16x32_f16(ahi[1], __builtin_bit_cast(half8, b1), cr, 0, 0, 0);    \
        cr = __builtin_amdgcn_mfma_f32_16x16x32_f16(ahi[2], __builtin_bit_cast(half8, b2), cr, 0, 0, 0);    \
        cr = __builtin_amdgcn_mfma_f32_16x16x32_f16(ahi[3], __builtin_bit_cast(half8, b3), cr, 0, 0, 0);    \
        __builtin_amdgcn_s_setprio(0);                                              \
        {   const float cnv_ = cnS[(NT) * 16 + l15];                                \
            const int kcur_ = (NT) * 16 + l15;                                      \
            _Pragma("unroll")                                                       \
            for (int r = 0; r < 4; ++r) {                                           \
                float v_ = cnv_ - 2.f * hh[r] - 0.001953125f * cr[r];               \
                if (v_ < best[r]) { best[r] = v_; bk[r] = kcur_; }                  \
            }                                                                       \
        }                                                                           \
        WAITSEQ;                                                                    \
    }

#define W4 do { VMWAIT4; RBARRIER; SCHEDB; } while (0)
#define W2 do { VMWAIT2; RBARRIER; SCHEDB; } while (0)
#define W0 do { VMWAIT0; RBARRIER; SCHEDB; } while (0)
#define WN do { } while (0)

#pragma unroll 1
    for (int t = 0; t < 61; ++t) {
        DO_PHASE(t, t + 3, 1, W4)
    }
    DO_PHASE(61, 0, 0, W2)   // outstanding {62,63} -> wait to 2: stage 62 landed
    DO_PHASE(62, 0, 0, W0)   // drain: stage 63 landed
    DO_PHASE(63, 0, 0, WN)   // last tile, no barrier
#undef DO_PHASE
#undef STAGE_ISSUE
#undef W4
#undef W2
#undef W0
#undef WN

    // argmin across the 16 centroid-columns within each 16-lane group
    // (masks < 16 keep lg fixed); numpy tie-break: smaller k
#pragma unroll
    for (int r = 0; r < 4; ++r) {
        float bv = best[r]; int bi = bk[r];
#pragma unroll
        for (int m = 1; m < 16; m <<= 1) {
            float ov = __shfl_xor(bv, m);
            int oi = __shfl_xor(bi, m);
            if (ov < bv || (ov == bv && oi < bi)) { bv = ov; bi = oi; }
        }
        best[r] = bv; bk[r] = bi;
    }

    // D layout (m89-verified): col = lane&15, row = (lane>>4)*4 + r
    float xnv[4];
#pragma unroll
    for (int r = 0; r < 4; ++r)
        xnv[r] = __shfl(xs, lg * 4 + r);   // xs of point (lg*4+r) lives in lane (lg*4+r)

    if (l15 == 0) {
#pragma unroll
        for (int r = 0; r < 4; ++r) {
            int m = lg * 4 + r;
            float sq = xnv[r] + best[r];
            min_d[p0 + m] = sqrtf(fmaxf(sq, 0.f));
            nearest[p0 + m] = bk[r];
        }
    }
}

// ---------------- kernel 2: per-batch stats + histogram + normalize (1024 threads) ----------------
__global__ void finalize_kernel(const float* __restrict__ min_d, const int* __restrict__ nearest,
                                const float* __restrict__ weights, float* __restrict__ out) {
    __shared__ float red[1024];
    __shared__ int hist[KK];
    __shared__ float bc[2];  // mean, thr
    const int b = blockIdx.x;
    const int tid = threadIdx.x;
    const float* md = min_d + (size_t)b * NN;
    const int* nr = nearest + (size_t)b * NN;

    // pass A: mean (two-pass std to match numpy numerics)
    float s = 0.f;
#pragma unroll
    for (int j = 0; j < NN / 1024; ++j) s += md[tid + 1024 * j];
    red[tid] = s;
    __syncthreads();
    for (int off = 512; off > 0; off >>= 1) {
        if (tid < off) red[tid] += red[tid + off];
        __syncthreads();
    }
    if (tid == 0) bc[0] = red[0] / (float)NN;
    __syncthreads();
    const float mean = bc[0];

    // pass B: sum of squared deviations -> thr = mean + std(ddof=1)
    float ss = 0.f;
#pragma unroll
    for (int j = 0; j < NN / 1024; ++j) {
        float v = md[tid + 1024 * j] - mean;
        ss += v * v;
    }
    red[tid] = ss;
    __syncthreads();
    for (int off = 512; off > 0; off >>= 1) {
        if (tid < off) red[tid] += red[tid + off];
        __syncthreads();
    }
    if (tid == 0) bc[1] = mean + sqrtf(red[0] / (float)(NN - 1));

    // histogram of masked assignments
    hist[tid] = 0;
    __syncthreads();
    const float thr = bc[1];
#pragma unroll
    for (int j = 0; j < NN / 1024; ++j) {
        int i = tid + 1024 * j;
        if (md[i] < thr) atomicAdd(&hist[nr[i]], 1);
    }
    __syncthreads();

    // asmk = counts*weights; L2-normalize the row (one k per thread)
    const float a = (float)hist[tid] * weights[tid];
    red[tid] = a * a;
    __syncthreads();
    for (int off = 512; off > 0; off >>= 1) {
        if (tid < off) red[tid] += red[tid + off];
        __syncthreads();
    }
    const float norm = sqrtf(red[0]);
    const float scale = 1.f / fmaxf(norm, 1e-12f);
    out[(size_t)b * KK + tid] = a * scale;
}

extern "C" void kernel_launch(void* const* d_in, const int* in_sizes, int n_in,
                              void* d_out, int out_size, void* d_ws, size_t ws_size,
                              hipStream_t stream) {
    const float* x = (const float*)d_in[0];
    const float* cent = (const float*)d_in[1];
    const float* weights = (const float*)d_in[2];
    float* out = (float*)d_out;

    char* ws = (char*)d_ws;
    float* min_d   = (float*)(ws + 0);
    int*   nearest = (int*)  (ws + 262144);
    float* cn      = (float*)(ws + 524288);
    uint4* cfh     = (uint4*)(ws + 528384);
    uint4* cfl     = (uint4*)(ws + 790528);

    prep_kernel<<<320, 256, 0, stream>>>(cent, cfh, cfl, cn);
    assign_mfma10<<<NPTS / 64, 256, 0, stream>>>(x, cfh, cfl, cn, min_d, nearest);
    finalize_kernel<<<BB, 1024, 0, stream>>>(min_d, nearest, weights, out);
}